// Round 1
// baseline (1514.991 us; speedup 1.0000x reference)
//
#include <hip/hip_runtime.h>
#include <hip/hip_fp16.h>

#define N_NODES 100000
#define N_EDGES 500000
#define M_PAD   100096   // 782 * 128
#define NCHUNK  196      // ceil(N_NODES / 512)
#define DEN_ELEMS (3 * M_PAD * 4)

using f32x4  = __attribute__((ext_vector_type(4))) float;
using bf16x8 = __attribute__((ext_vector_type(8))) __bf16;

__device__ __forceinline__ ushort f2bf(float f) {
  union { float f; unsigned u; } v; v.f = f;
  unsigned r = v.u + 0x7fffu + ((v.u >> 16) & 1u);   // RNE
  return (ushort)(r >> 16);
}
__device__ __forceinline__ float bf2f(ushort b) {
  union { unsigned u; float f; } v; v.u = ((unsigned)b) << 16;
  return v.f;
}

// ---------------------------------------------------------------------------
// Conversions
// ---------------------------------------------------------------------------
__global__ __launch_bounds__(256) void cvt_x_kernel(const float* __restrict__ x,
                                                    ushort* __restrict__ h) {
  const size_t i = (size_t)blockIdx.x * 256 + threadIdx.x;  // float4 index
  ushort4 o;
  if (i < (size_t)N_NODES * 64) {
    const float4 v = ((const float4*)x)[i];
    o.x = f2bf(v.x); o.y = f2bf(v.y); o.z = f2bf(v.z); o.w = f2bf(v.w);
  } else {
    o.x = 0; o.y = 0; o.z = 0; o.w = 0;   // zero pad rows -> zero feat rows
  }
  ((ushort4*)h)[i] = o;
}

// W [le][k][n] fp32 -> Wt [le][n][k] bf16
__global__ __launch_bounds__(256) void cvt_w_kernel(const float* __restrict__ W,
                                                    ushort* __restrict__ Wt) {
  const int i = blockIdx.x * 256 + threadIdx.x;       // 6*65536
  const int le = i >> 16, r = i & 65535, nn = r >> 8, kk = r & 255;
  Wt[i] = f2bf(W[(le << 16) | (kk << 8) | nn]);
}

// W_out [256][349] -> Wto [384][256] bf16 transposed, zero-padded cols
__global__ __launch_bounds__(256) void cvt_wout_kernel(const float* __restrict__ Wo,
                                                       ushort* __restrict__ Wto) {
  const int i = blockIdx.x * 256 + threadIdx.x;       // 384*256
  const int nn = i >> 8, kk = i & 255;
  Wto[i] = f2bf(nn < 349 ? Wo[kk * 349 + nn] : 0.f);
}

// ---------------------------------------------------------------------------
// Combined CSR build (by dst, all 3 etypes merged per node). dst is
// layer-invariant so built once per call. srcid/dstid store et*M_PAD + node,
// i.e. precomputed row ids into feat / el / er / den.
// ---------------------------------------------------------------------------
__global__ __launch_bounds__(256) void zero_cnt_kernel(int* __restrict__ cnt) {
  const int i = blockIdx.x * 256 + threadIdx.x;
  if (i < N_NODES) cnt[i] = 0;
}

__global__ __launch_bounds__(256) void hist_kernel(const int* __restrict__ dst,
                                                   int* __restrict__ cnt) {
  const int i = blockIdx.x * 256 + threadIdx.x;
  if (i >= 3 * N_EDGES) return;
  atomicAdd(&cnt[dst[i]], 1);
}

__global__ __launch_bounds__(512) void scan1_kernel(const int* __restrict__ cnt,
                                                    int* __restrict__ rowp,
                                                    int* __restrict__ bsum) {
  __shared__ int sm[512];
  const int c = blockIdx.x, tid = threadIdx.x;
  const int idx = c * 512 + tid;
  const int v = (idx < N_NODES) ? cnt[idx] : 0;
  sm[tid] = v; __syncthreads();
  for (int off = 1; off < 512; off <<= 1) {
    const int tmp = (tid >= off) ? sm[tid - off] : 0;
    __syncthreads();
    sm[tid] += tmp;
    __syncthreads();
  }
  if (idx < N_NODES) rowp[idx] = sm[tid] - v;  // exclusive
  if (tid == 511) bsum[c] = sm[511];
}

__global__ __launch_bounds__(256) void scan2_kernel(int* __restrict__ bsum) {
  __shared__ int sm[256];
  const int tid = threadIdx.x;
  const int v = (tid < NCHUNK) ? bsum[tid] : 0;
  sm[tid] = v; __syncthreads();
  for (int off = 1; off < 256; off <<= 1) {
    const int tmp = (tid >= off) ? sm[tid - off] : 0;
    __syncthreads();
    sm[tid] += tmp;
    __syncthreads();
  }
  if (tid < NCHUNK) bsum[tid] = sm[tid] - v;          // exclusive
}

__global__ __launch_bounds__(512) void scan3_kernel(int* __restrict__ rowp,
                                                    const int* __restrict__ bsum,
                                                    int* __restrict__ cur) {
  const int c = blockIdx.x, tid = threadIdx.x;
  const int idx = c * 512 + tid;
  if (idx < N_NODES) {
    const int v = rowp[idx] + bsum[c];
    rowp[idx] = v;
    cur[idx] = v;
  }
  if (c == 0 && tid == 0) rowp[N_NODES] = 3 * N_EDGES;
}

__global__ __launch_bounds__(256) void scatter_kernel(const int* __restrict__ src,
                                                      const int* __restrict__ dst,
                                                      int* __restrict__ cur,
                                                      uint* __restrict__ srcid,
                                                      uint* __restrict__ dstid) {
  const int i = blockIdx.x * 256 + threadIdx.x;
  if (i >= 3 * N_EDGES) return;
  const int et = i / N_EDGES;
  const int d = dst[i];
  const int pos = atomicAdd(&cur[d], 1);
  srcid[pos] = (uint)(et * M_PAD + src[i]);
  dstid[pos] = (uint)(et * M_PAD + d);
}

// ---------------------------------------------------------------------------
// Fused feat GEMM: 128x128 tile for all 3 etypes, shared A tile; epilogue
// writes feat (bf16) and el/er (pitch M_PAD) via in-register head-dots.
// ---------------------------------------------------------------------------
__global__ __launch_bounds__(256, 2) void gemm_feat_fused(
    const ushort* __restrict__ A, const ushort* __restrict__ WtL,
    ushort* __restrict__ feat, const float* __restrict__ attn_l,
    const float* __restrict__ attn_r, float* __restrict__ el,
    float* __restrict__ er, int layer) {
  __shared__ ushort As[128 * 64];
  __shared__ ushort Bs[3 * 128 * 64];
  const int t = threadIdx.x;
  const int lane = t & 63;
  const int wave = t >> 6;
  const int wm = (wave >> 1) << 6;
  const int wn = (wave & 1) << 6;
  const int quad = lane >> 4;
  const int ln = lane & 15;
  const size_t m0 = (size_t)blockIdx.x * 128;
  const size_t n0 = (size_t)blockIdx.y * 128;

  f32x4 acc[3][4][4];
#pragma unroll
  for (int e = 0; e < 3; ++e)
#pragma unroll
    for (int x = 0; x < 4; ++x)
#pragma unroll
      for (int y = 0; y < 4; ++y)
        acc[e][x][y] = (f32x4){0.f, 0.f, 0.f, 0.f};

  for (int k0 = 0; k0 < 256; k0 += 64) {
    __syncthreads();
#pragma unroll
    for (int i = 0; i < 4; ++i) {
      const int f = i * 256 + t;
      const int row = f >> 3;
      const int cl = (f & 7) ^ (row & 7);                 // global-side swizzle
      const int ldsbase = (i * 256 + (t & ~63)) << 3;     // wave-uniform, ushort idx
      __builtin_amdgcn_global_load_lds(
          (const __attribute__((address_space(1))) void*)(A + (m0 + row) * 256 + k0 + cl * 8),
          (__attribute__((address_space(3))) void*)(As + ldsbase), 16, 0, 0);
#pragma unroll
      for (int e = 0; e < 3; ++e)
        __builtin_amdgcn_global_load_lds(
            (const __attribute__((address_space(1))) void*)(WtL + (e << 16) + (n0 + row) * 256 + k0 + cl * 8),
            (__attribute__((address_space(3))) void*)(Bs + e * 8192 + ldsbase), 16, 0, 0);
    }
    __syncthreads();
#pragma unroll
    for (int s = 0; s < 2; ++s) {
      const int cl = s * 4 + quad;
      bf16x8 af[4];
#pragma unroll
      for (int x = 0; x < 4; ++x) {
        const int mm = wm + x * 16 + ln;
        af[x] = *(const bf16x8*)(As + mm * 64 + ((cl ^ (mm & 7)) << 3));
      }
#pragma unroll
      for (int e = 0; e < 3; ++e) {
        bf16x8 bfr[4];
#pragma unroll
        for (int y = 0; y < 4; ++y) {
          const int nn = wn + y * 16 + ln;
          bfr[y] = *(const bf16x8*)(Bs + e * 8192 + nn * 64 + ((cl ^ (nn & 7)) << 3));
        }
#pragma unroll
        for (int x = 0; x < 4; ++x)
#pragma unroll
          for (int y = 0; y < 4; ++y)
            acc[e][x][y] = __builtin_amdgcn_mfma_f32_16x16x32_bf16(bfr[y], af[x], acc[e][x][y], 0, 0, 0);
      }
    }
  }

  const int h = (int)(n0 + wn) >> 6;                      // this wave's head
#pragma unroll
  for (int e = 0; e < 3; ++e) {
    ushort* C = feat + (size_t)e * M_PAD * 256;
#pragma unroll
    for (int x = 0; x < 4; ++x) {
      const size_t m = m0 + wm + x * 16 + ln;
#pragma unroll
      for (int y = 0; y < 4; ++y) {
        const size_t n = n0 + wn + y * 16 + quad * 4;
        ushort4 o;
        o.x = f2bf(acc[e][x][y][0]); o.y = f2bf(acc[e][x][y][1]);
        o.z = f2bf(acc[e][x][y][2]); o.w = f2bf(acc[e][x][y][3]);
        *(ushort4*)(C + m * 256 + n) = o;
      }
    }
    const float* al = attn_l + (((layer * 3 + e) * 4 + h) << 6);
    const float* ar = attn_r + (((layer * 3 + e) * 4 + h) << 6);
    float4 alv[4], arv[4];
#pragma unroll
    for (int y = 0; y < 4; ++y) {
      alv[y] = *(const float4*)(al + y * 16 + quad * 4);
      arv[y] = *(const float4*)(ar + y * 16 + quad * 4);
    }
#pragma unroll
    for (int x = 0; x < 4; ++x) {
      float pl = 0.f, pr = 0.f;
#pragma unroll
      for (int y = 0; y < 4; ++y) {
        pl += acc[e][x][y][0] * alv[y].x + acc[e][x][y][1] * alv[y].y +
              acc[e][x][y][2] * alv[y].z + acc[e][x][y][3] * alv[y].w;
        pr += acc[e][x][y][0] * arv[y].x + acc[e][x][y][1] * arv[y].y +
              acc[e][x][y][2] * arv[y].z + acc[e][x][y][3] * arv[y].w;
      }
      pl += __shfl_xor(pl, 16); pl += __shfl_xor(pl, 32);
      pr += __shfl_xor(pr, 16); pr += __shfl_xor(pr, 32);
      const int m = (int)m0 + wm + x * 16 + ln;
      if (quad == 0 && m < N_NODES) {
        el[((size_t)e * M_PAD + m) * 4 + h] = pl;
        er[((size_t)e * M_PAD + m) * 4 + h] = pr;
      }
    }
  }
}

// ---------------------------------------------------------------------------
// Final classifier GEMM (fp32 out + bias, guarded).
// ---------------------------------------------------------------------------
__global__ __launch_bounds__(256) void gemm128(const ushort* __restrict__ A,
                                               const ushort* __restrict__ Bt,
                                               float* __restrict__ C,
                                               const float* __restrict__ obias,
                                               int ldc, int nmax, int mmax) {
  __shared__ ushort As[128 * 64];
  __shared__ ushort Bs[128 * 64];
  const int t = threadIdx.x;
  const int lane = t & 63;
  const int wave = t >> 6;
  const int wm = (wave >> 1) << 6;
  const int wn = (wave & 1) << 6;
  const int quad = lane >> 4;
  const int ln = lane & 15;
  const size_t m0 = (size_t)blockIdx.x * 128;
  const size_t n0 = (size_t)blockIdx.y * 128;

  f32x4 acc[4][4];
#pragma unroll
  for (int x = 0; x < 4; ++x)
#pragma unroll
    for (int y = 0; y < 4; ++y)
      acc[x][y] = (f32x4){0.f, 0.f, 0.f, 0.f};

  for (int k0 = 0; k0 < 256; k0 += 64) {
    __syncthreads();
#pragma unroll
    for (int i = 0; i < 4; ++i) {
      const int f = i * 256 + t;
      const int row = f >> 3;
      const int cl = (f & 7) ^ (row & 7);
      const int ldsbase = (i * 256 + (t & ~63)) << 3;
      __builtin_amdgcn_global_load_lds(
          (const __attribute__((address_space(1))) void*)(A + (m0 + row) * 256 + k0 + cl * 8),
          (__attribute__((address_space(3))) void*)(As + ldsbase), 16, 0, 0);
      __builtin_amdgcn_global_load_lds(
          (const __attribute__((address_space(1))) void*)(Bt + (n0 + row) * 256 + k0 + cl * 8),
          (__attribute__((address_space(3))) void*)(Bs + ldsbase), 16, 0, 0);
    }
    __syncthreads();
#pragma unroll
    for (int s = 0; s < 2; ++s) {
      bf16x8 af[4], bfr[4];
      const int cl = s * 4 + quad;
#pragma unroll
      for (int x = 0; x < 4; ++x) {
        const int mm = wm + x * 16 + ln;
        af[x] = *(const bf16x8*)(As + mm * 64 + ((cl ^ (mm & 7)) << 3));
        const int nn = wn + x * 16 + ln;
        bfr[x] = *(const bf16x8*)(Bs + nn * 64 + ((cl ^ (nn & 7)) << 3));
      }
#pragma unroll
      for (int x = 0; x < 4; ++x)
#pragma unroll
        for (int y = 0; y < 4; ++y)
          acc[x][y] = __builtin_amdgcn_mfma_f32_16x16x32_bf16(bfr[y], af[x], acc[x][y], 0, 0, 0);
    }
  }

#pragma unroll
  for (int x = 0; x < 4; ++x) {
    const int m = (int)m0 + wm + x * 16 + ln;
    if (m < mmax) {
#pragma unroll
      for (int y = 0; y < 4; ++y) {
        const int n = (int)n0 + wn + y * 16 + quad * 4;
#pragma unroll
        for (int r = 0; r < 4; ++r)
          if (n + r < nmax)
            C[(size_t)m * ldc + n + r] = acc[x][y][r] + obias[n + r];
      }
    }
  }
}

// ---------------------------------------------------------------------------
// Per-edge attention weights in combined-CSR order (fp16) + fp32 denominator
// accumulation (atomics into L2-resident 4.8 MB buffer).
// ---------------------------------------------------------------------------
__global__ __launch_bounds__(256) void wcalc_kernel(const uint* __restrict__ srcid,
                                                    const uint* __restrict__ dstid,
                                                    const float* __restrict__ el,
                                                    const float* __restrict__ er,
                                                    ushort* __restrict__ wcsr,
                                                    float* __restrict__ den) {
  const int i = blockIdx.x * 256 + threadIdx.x;
  if (i >= 3 * N_EDGES) return;
  const uint sid = srcid[i];
  const uint did = dstid[i];
  const float4 l4 = ((const float4*)el)[sid];
  const float4 r4 = ((const float4*)er)[did];
  float z0 = l4.x + r4.x, z1 = l4.y + r4.y, z2 = l4.z + r4.z, z3 = l4.w + r4.w;
  z0 = (z0 > 0.f) ? z0 : 0.2f * z0;
  z1 = (z1 > 0.f) ? z1 : 0.2f * z1;
  z2 = (z2 > 0.f) ? z2 : 0.2f * z2;
  z3 = (z3 > 0.f) ? z3 : 0.2f * z3;
  const float w0 = __expf(z0), w1 = __expf(z1), w2 = __expf(z2), w3 = __expf(z3);
  ushort4 o;
  o.x = __half_as_ushort(__float2half(w0));
  o.y = __half_as_ushort(__float2half(w1));
  o.z = __half_as_ushort(__float2half(w2));
  o.w = __half_as_ushort(__float2half(w3));
  ((ushort4*)wcsr)[i] = o;
  float* dp = den + (size_t)did * 4;
  atomicAdd(dp + 0, w0); atomicAdd(dp + 1, w1);
  atomicAdd(dp + 2, w2); atomicAdd(dp + 3, w3);
}

__global__ __launch_bounds__(256) void zero_den_kernel(float* __restrict__ den) {
  const int i = blockIdx.x * 256 + threadIdx.x;
  if (i < DEN_ELEMS) den[i] = 0.f;
}

__global__ __launch_bounds__(256) void rcp_den_kernel(float* __restrict__ den) {
  const int i = blockIdx.x * 256 + threadIdx.x;
  if (i < DEN_ELEMS) {
    const float d = den[i];
    den[i] = (d != 0.f) ? __builtin_amdgcn_rcpf(d) : 0.f;
  }
}

// w' = w * (1/den[dst]) : weights become pre-normalized alphas <= ~1.
__global__ __launch_bounds__(256) void wnorm_kernel(const uint* __restrict__ dstid,
                                                    const float* __restrict__ rden,
                                                    ushort* __restrict__ wcsr) {
  const int i = blockIdx.x * 256 + threadIdx.x;
  if (i >= 3 * N_EDGES) return;
  const uint did = dstid[i];
  const float4 r4 = ((const float4*)rden)[did];
  const ushort4 w = ((const ushort4*)wcsr)[i];
  ushort4 o;
  o.x = __half_as_ushort(__float2half(__half2float(__ushort_as_half(w.x)) * r4.x));
  o.y = __half_as_ushort(__float2half(__half2float(__ushort_as_half(w.y)) * r4.y));
  o.z = __half_as_ushort(__float2half(__half2float(__ushort_as_half(w.z)) * r4.z));
  o.w = __half_as_ushort(__float2half(__half2float(__ushort_as_half(w.w)) * r4.w));
  ((ushort4*)wcsr)[i] = o;
}

// ---------------------------------------------------------------------------
// Aggregation v4: combined CSR (all etypes per node, pre-normalized weights)
// -> single flat sum, no per-etype denominators. Wave-strided node loop
// (2048 resident blocks) removes block-granularity load imbalance. Node id is
// readfirstlane'd so rowp/srcid reads become scalar loads and every gather is
// SGPR-base + lane-constant voffset (near-zero VALU per edge).
// ---------------------------------------------------------------------------
__global__ __launch_bounds__(256) void agg_kernel(const ushort* __restrict__ feat,
                                                  const ushort* __restrict__ wcsr,
                                                  const int* __restrict__ rowp,
                                                  const uint* __restrict__ srcid,
                                                  const float* __restrict__ bias,
                                                  ushort* __restrict__ hout,
                                                  int layer, int do_relu) {
  const int wv   = __builtin_amdgcn_readfirstlane((int)(threadIdx.x >> 6));
  const int lane = threadIdx.x & 63;
  const int h2   = (lane >> 4) << 1;          // byte offset into 8B weight rec
  const int f8   = lane << 3;                 // byte offset into 512B feat row
  const float* bl = bias + layer * 768 + (lane << 2);
  const float b0 = bl[0] + bl[256] + bl[512];
  const float b1 = bl[1] + bl[257] + bl[513];
  const float b2 = bl[2] + bl[258] + bl[514];
  const float b3 = bl[3] + bl[259] + bl[515];
  const char* wb = (const char*)wcsr;
  const char* fb = (const char*)feat;
  for (int n = blockIdx.x * 4 + wv; n < N_NODES; n += 8192) {
    const int beg = rowp[n];
    const int end = rowp[n + 1];
    float a0 = b0, a1 = b1, a2 = b2, a3 = b3;
    if (end > beg) {
      const int last = end - 1;
      float l0 = 0.f, l1 = 0.f, l2 = 0.f, l3 = 0.f;
      for (int i = beg; i < end; i += 8) {
        int idx[8];
#pragma unroll
        for (int j = 0; j < 8; ++j)
          idx[j] = (i + j < last) ? (i + j) : last;   // clamp: always valid
        uint sd[8];
#pragma unroll
        for (int j = 0; j < 8; ++j)
          sd[j] = srcid[idx[j]];
        float wj[8];
#pragma unroll
        for (int j = 0; j < 8; ++j) {
          const ushort wu = *(const ushort*)(wb + ((size_t)idx[j] << 3) + h2);
          const float t = __half2float(__ushort_as_half(wu));
          wj[j] = (i + j <= last) ? t : 0.f;          // branchless remainder
        }
        uint2 fv[8];
#pragma unroll
        for (int j = 0; j < 8; ++j)
          fv[j] = *(const uint2*)(fb + ((size_t)sd[j] << 9) + f8);
#pragma unroll
        for (int j = 0; j < 8; ++j) {
          union { uint u; float f; } c0, c1, c2, c3;
          c0.u = fv[j].x << 16;
          c1.u = fv[j].x & 0xffff0000u;
          c2.u = fv[j].y << 16;
          c3.u = fv[j].y & 0xffff0000u;
          l0 += wj[j] * c0.f;
          l1 += wj[j] * c1.f;
          l2 += wj[j] * c2.f;
          l3 += wj[j] * c3.f;
        }
      }
      a0 += l0; a1 += l1; a2 += l2; a3 += l3;
    }
    if (do_relu) {
      a0 = fmaxf(a0, 0.f); a1 = fmaxf(a1, 0.f);
      a2 = fmaxf(a2, 0.f); a3 = fmaxf(a3, 0.f);
    }
    ushort4 o;
    o.x = f2bf(a0); o.y = f2bf(a1); o.z = f2bf(a2); o.w = f2bf(a3);
    *(ushort4*)(hout + (size_t)n * 256 + (lane << 2)) = o;
  }
}

// ---------------------------------------------------------------------------
extern "C" void kernel_launch(void* const* d_in, const int* in_sizes, int n_in,
                              void* d_out, int out_size, void* d_ws, size_t ws_size,
                              hipStream_t stream) {
  const float* x      = (const float*)d_in[0];
  const float* W      = (const float*)d_in[1];
  const float* attn_l = (const float*)d_in[2];
  const float* attn_r = (const float*)d_in[3];
  const float* bias   = (const float*)d_in[4];
  const float* W_out  = (const float*)d_in[5];
  const float* b_out  = (const float*)d_in[6];
  const int*   src    = (const int*)d_in[7];
  const int*   dst    = (const int*)d_in[8];

  char* p = (char*)d_ws;
  auto carve = [&](size_t bytes) {
    char* r = p;
    p += (bytes + 255) & ~(size_t)255;
    return r;
  };
  ushort* h_bf  = (ushort*)carve((size_t)M_PAD * 256 * 2);        //  51.2 MB
  ushort* feat  = (ushort*)carve((size_t)3 * M_PAD * 256 * 2);    // 153.7 MB
  ushort* Wt    = (ushort*)carve((size_t)6 * 65536 * 2);
  ushort* Wto   = (ushort*)carve((size_t)384 * 256 * 2);
  float*  el    = (float*)carve((size_t)3 * M_PAD * 4 * 4);       //   4.8 MB
  float*  er    = (float*)carve((size_t)3 * M_PAD * 4 * 4);       //   4.8 MB
  float*  den   = (float*)carve((size_t)DEN_ELEMS * 4);           //   4.8 MB
  int*    cnt   = (int*)carve((size_t)N_NODES * 4);
  int*    rowp  = (int*)carve((size_t)(N_NODES + 1) * 4);
  int*    cur   = (int*)carve((size_t)N_NODES * 4);
  uint*   srcid = (uint*)carve((size_t)3 * N_EDGES * 4);          //   6 MB
  uint*   dstid = (uint*)carve((size_t)3 * N_EDGES * 4);          //   6 MB
  ushort* wcsr  = (ushort*)carve((size_t)3 * N_EDGES * 4 * 2);    //  12 MB (fp16)
  int*    bsum  = (int*)carve((size_t)NCHUNK * 4);

  cvt_x_kernel<<<M_PAD * 64 / 256, 256, 0, stream>>>(x, h_bf);
  cvt_w_kernel<<<6 * 65536 / 256, 256, 0, stream>>>(W, Wt);
  cvt_wout_kernel<<<384 * 256 / 256, 256, 0, stream>>>(W_out, Wto);

  zero_cnt_kernel<<<(N_NODES + 255) / 256, 256, 0, stream>>>(cnt);
  hist_kernel<<<(3 * N_EDGES + 255) / 256, 256, 0, stream>>>(dst, cnt);
  scan1_kernel<<<NCHUNK, 512, 0, stream>>>(cnt, rowp, bsum);
  scan2_kernel<<<1, 256, 0, stream>>>(bsum);
  scan3_kernel<<<NCHUNK, 512, 0, stream>>>(rowp, bsum, cur);
  scatter_kernel<<<(3 * N_EDGES + 255) / 256, 256, 0, stream>>>(src, dst, cur, srcid, dstid);

  for (int l = 0; l < 2; ++l) {
    gemm_feat_fused<<<dim3(M_PAD / 128, 2), 256, 0, stream>>>(
        h_bf, Wt + (size_t)l * 3 * 65536, feat, attn_l, attn_r, el, er, l);
    zero_den_kernel<<<(DEN_ELEMS + 255) / 256, 256, 0, stream>>>(den);
    wcalc_kernel<<<(3 * N_EDGES + 255) / 256, 256, 0, stream>>>(srcid, dstid, el, er, wcsr, den);
    rcp_den_kernel<<<(DEN_ELEMS + 255) / 256, 256, 0, stream>>>(den);
    wnorm_kernel<<<(3 * N_EDGES + 255) / 256, 256, 0, stream>>>(dstid, den, wcsr);
    agg_kernel<<<2048, 256, 0, stream>>>(feat, wcsr, rowp, srcid, bias,
                                         h_bf, l, l == 0 ? 1 : 0);
  }
  gemm128<<<dim3(M_PAD / 128, 3), 256, 0, stream>>>(h_bf, Wto, (float*)d_out,
                                                    b_out, 349, 349, N_NODES);
}

// Round 2
// 989.792 us; speedup vs baseline: 1.5306x; 1.5306x over previous
//
#include <hip/hip_runtime.h>
#include <hip/hip_fp16.h>

#define N_NODES 100000
#define N_EDGES 500000
#define M_PAD   100096   // 782 * 128
#define N3      300000   // 3 * N_NODES (node-major, etype-minor counts)
#define NCHUNK3 586      // ceil(N3 / 512)

using f32x4  = __attribute__((ext_vector_type(4))) float;
using bf16x8 = __attribute__((ext_vector_type(8))) __bf16;

__device__ __forceinline__ ushort f2bf(float f) {
  union { float f; unsigned u; } v; v.f = f;
  unsigned r = v.u + 0x7fffu + ((v.u >> 16) & 1u);   // RNE
  return (ushort)(r >> 16);
}
__device__ __forceinline__ float bf2f(ushort b) {
  union { unsigned u; float f; } v; v.u = ((unsigned)b) << 16;
  return v.f;
}

// ---------------------------------------------------------------------------
// Conversions
// ---------------------------------------------------------------------------
__global__ __launch_bounds__(256) void cvt_x_kernel(const float* __restrict__ x,
                                                    ushort* __restrict__ h) {
  const size_t i = (size_t)blockIdx.x * 256 + threadIdx.x;  // float4 index
  ushort4 o;
  if (i < (size_t)N_NODES * 64) {
    const float4 v = ((const float4*)x)[i];
    o.x = f2bf(v.x); o.y = f2bf(v.y); o.z = f2bf(v.z); o.w = f2bf(v.w);
  } else {
    o.x = 0; o.y = 0; o.z = 0; o.w = 0;   // zero pad rows -> zero feat rows
  }
  ((ushort4*)h)[i] = o;
}

// W [le][k][n] fp32 -> Wt [le][n][k] bf16
__global__ __launch_bounds__(256) void cvt_w_kernel(const float* __restrict__ W,
                                                    ushort* __restrict__ Wt) {
  const int i = blockIdx.x * 256 + threadIdx.x;       // 6*65536
  const int le = i >> 16, r = i & 65535, nn = r >> 8, kk = r & 255;
  Wt[i] = f2bf(W[(le << 16) | (kk << 8) | nn]);
}

// W_out [256][349] -> Wto [384][256] bf16 transposed, zero-padded cols
__global__ __launch_bounds__(256) void cvt_wout_kernel(const float* __restrict__ Wo,
                                                       ushort* __restrict__ Wto) {
  const int i = blockIdx.x * 256 + threadIdx.x;       // 384*256
  const int nn = i >> 8, kk = i & 255;
  Wto[i] = f2bf(nn < 349 ? Wo[kk * 349 + nn] : 0.f);
}

// ---------------------------------------------------------------------------
// Combined CSR build, grouped by (dst node, etype): segment (n,et) is
// contiguous, node n's full row is [rowp3[3n], rowp3[3n+3]). srcid stores
// et*M_PAD + src (precomputed row id into feat / el).
// ---------------------------------------------------------------------------
__global__ __launch_bounds__(256) void zero_cnt_kernel(int* __restrict__ cnt) {
  const int i = blockIdx.x * 256 + threadIdx.x;
  if (i < N3) cnt[i] = 0;
}

__global__ __launch_bounds__(256) void hist_kernel(const int* __restrict__ dst,
                                                   int* __restrict__ cnt) {
  const int i = blockIdx.x * 256 + threadIdx.x;
  if (i >= 3 * N_EDGES) return;
  const int et = i / N_EDGES;
  atomicAdd(&cnt[dst[i] * 3 + et], 1);
}

__global__ __launch_bounds__(512) void scan1_kernel(const int* __restrict__ cnt,
                                                    int* __restrict__ rowp3,
                                                    int* __restrict__ bsum) {
  __shared__ int sm[512];
  const int c = blockIdx.x, tid = threadIdx.x;
  const int idx = c * 512 + tid;
  const int v = (idx < N3) ? cnt[idx] : 0;
  sm[tid] = v; __syncthreads();
  for (int off = 1; off < 512; off <<= 1) {
    const int tmp = (tid >= off) ? sm[tid - off] : 0;
    __syncthreads();
    sm[tid] += tmp;
    __syncthreads();
  }
  if (idx < N3) rowp3[idx] = sm[tid] - v;  // exclusive
  if (tid == 511) bsum[c] = sm[511];
}

__global__ __launch_bounds__(1024) void scan2_kernel(int* __restrict__ bsum) {
  __shared__ int sm[1024];
  const int tid = threadIdx.x;
  const int v = (tid < NCHUNK3) ? bsum[tid] : 0;
  sm[tid] = v; __syncthreads();
  for (int off = 1; off < 1024; off <<= 1) {
    const int tmp = (tid >= off) ? sm[tid - off] : 0;
    __syncthreads();
    sm[tid] += tmp;
    __syncthreads();
  }
  if (tid < NCHUNK3) bsum[tid] = sm[tid] - v;          // exclusive
}

__global__ __launch_bounds__(512) void scan3_kernel(int* __restrict__ rowp3,
                                                    const int* __restrict__ bsum,
                                                    int* __restrict__ cur) {
  const int c = blockIdx.x, tid = threadIdx.x;
  const int idx = c * 512 + tid;
  if (idx < N3) {
    const int v = rowp3[idx] + bsum[c];
    rowp3[idx] = v;
    cur[idx] = v;
  }
  if (c == 0 && tid == 0) rowp3[N3] = 3 * N_EDGES;
}

__global__ __launch_bounds__(256) void scatter_kernel(const int* __restrict__ src,
                                                      const int* __restrict__ dst,
                                                      int* __restrict__ cur,
                                                      uint* __restrict__ srcid) {
  const int i = blockIdx.x * 256 + threadIdx.x;
  if (i >= 3 * N_EDGES) return;
  const int et = i / N_EDGES;
  const int d = dst[i];
  const int pos = atomicAdd(&cur[d * 3 + et], 1);
  srcid[pos] = (uint)(et * M_PAD + src[i]);
}

// ---------------------------------------------------------------------------
// Fused feat GEMM: 128x128 tile for all 3 etypes, shared A tile; epilogue
// writes feat (bf16) and el/er (pitch M_PAD) via in-register head-dots.
// ---------------------------------------------------------------------------
__global__ __launch_bounds__(256, 2) void gemm_feat_fused(
    const ushort* __restrict__ A, const ushort* __restrict__ WtL,
    ushort* __restrict__ feat, const float* __restrict__ attn_l,
    const float* __restrict__ attn_r, float* __restrict__ el,
    float* __restrict__ er, int layer) {
  __shared__ ushort As[128 * 64];
  __shared__ ushort Bs[3 * 128 * 64];
  const int t = threadIdx.x;
  const int lane = t & 63;
  const int wave = t >> 6;
  const int wm = (wave >> 1) << 6;
  const int wn = (wave & 1) << 6;
  const int quad = lane >> 4;
  const int ln = lane & 15;
  const size_t m0 = (size_t)blockIdx.x * 128;
  const size_t n0 = (size_t)blockIdx.y * 128;

  f32x4 acc[3][4][4];
#pragma unroll
  for (int e = 0; e < 3; ++e)
#pragma unroll
    for (int x = 0; x < 4; ++x)
#pragma unroll
      for (int y = 0; y < 4; ++y)
        acc[e][x][y] = (f32x4){0.f, 0.f, 0.f, 0.f};

  for (int k0 = 0; k0 < 256; k0 += 64) {
    __syncthreads();
#pragma unroll
    for (int i = 0; i < 4; ++i) {
      const int f = i * 256 + t;
      const int row = f >> 3;
      const int cl = (f & 7) ^ (row & 7);                 // global-side swizzle
      const int ldsbase = (i * 256 + (t & ~63)) << 3;     // wave-uniform, ushort idx
      __builtin_amdgcn_global_load_lds(
          (const __attribute__((address_space(1))) void*)(A + (m0 + row) * 256 + k0 + cl * 8),
          (__attribute__((address_space(3))) void*)(As + ldsbase), 16, 0, 0);
#pragma unroll
      for (int e = 0; e < 3; ++e)
        __builtin_amdgcn_global_load_lds(
            (const __attribute__((address_space(1))) void*)(WtL + (e << 16) + (n0 + row) * 256 + k0 + cl * 8),
            (__attribute__((address_space(3))) void*)(Bs + e * 8192 + ldsbase), 16, 0, 0);
    }
    __syncthreads();
#pragma unroll
    for (int s = 0; s < 2; ++s) {
      const int cl = s * 4 + quad;
      bf16x8 af[4];
#pragma unroll
      for (int x = 0; x < 4; ++x) {
        const int mm = wm + x * 16 + ln;
        af[x] = *(const bf16x8*)(As + mm * 64 + ((cl ^ (mm & 7)) << 3));
      }
#pragma unroll
      for (int e = 0; e < 3; ++e) {
        bf16x8 bfr[4];
#pragma unroll
        for (int y = 0; y < 4; ++y) {
          const int nn = wn + y * 16 + ln;
          bfr[y] = *(const bf16x8*)(Bs + e * 8192 + nn * 64 + ((cl ^ (nn & 7)) << 3));
        }
#pragma unroll
        for (int x = 0; x < 4; ++x)
#pragma unroll
          for (int y = 0; y < 4; ++y)
            acc[e][x][y] = __builtin_amdgcn_mfma_f32_16x16x32_bf16(bfr[y], af[x], acc[e][x][y], 0, 0, 0);
      }
    }
  }

  const int h = (int)(n0 + wn) >> 6;                      // this wave's head
#pragma unroll
  for (int e = 0; e < 3; ++e) {
    ushort* C = feat + (size_t)e * M_PAD * 256;
#pragma unroll
    for (int x = 0; x < 4; ++x) {
      const size_t m = m0 + wm + x * 16 + ln;
#pragma unroll
      for (int y = 0; y < 4; ++y) {
        const size_t n = n0 + wn + y * 16 + quad * 4;
        ushort4 o;
        o.x = f2bf(acc[e][x][y][0]); o.y = f2bf(acc[e][x][y][1]);
        o.z = f2bf(acc[e][x][y][2]); o.w = f2bf(acc[e][x][y][3]);
        *(ushort4*)(C + m * 256 + n) = o;
      }
    }
    const float* al = attn_l + (((layer * 3 + e) * 4 + h) << 6);
    const float* ar = attn_r + (((layer * 3 + e) * 4 + h) << 6);
    float4 alv[4], arv[4];
#pragma unroll
    for (int y = 0; y < 4; ++y) {
      alv[y] = *(const float4*)(al + y * 16 + quad * 4);
      arv[y] = *(const float4*)(ar + y * 16 + quad * 4);
    }
#pragma unroll
    for (int x = 0; x < 4; ++x) {
      float pl = 0.f, pr = 0.f;
#pragma unroll
      for (int y = 0; y < 4; ++y) {
        pl += acc[e][x][y][0] * alv[y].x + acc[e][x][y][1] * alv[y].y +
              acc[e][x][y][2] * alv[y].z + acc[e][x][y][3] * alv[y].w;
        pr += acc[e][x][y][0] * arv[y].x + acc[e][x][y][1] * arv[y].y +
              acc[e][x][y][2] * arv[y].z + acc[e][x][y][3] * arv[y].w;
      }
      pl += __shfl_xor(pl, 16); pl += __shfl_xor(pl, 32);
      pr += __shfl_xor(pr, 16); pr += __shfl_xor(pr, 32);
      const int m = (int)m0 + wm + x * 16 + ln;
      if (quad == 0 && m < N_NODES) {
        el[((size_t)e * M_PAD + m) * 4 + h] = pl;
        er[((size_t)e * M_PAD + m) * 4 + h] = pr;
      }
    }
  }
}

// ---------------------------------------------------------------------------
// Final classifier GEMM (fp32 out + bias, guarded).
// ---------------------------------------------------------------------------
__global__ __launch_bounds__(256) void gemm128(const ushort* __restrict__ A,
                                               const ushort* __restrict__ Bt,
                                               float* __restrict__ C,
                                               const float* __restrict__ obias,
                                               int ldc, int nmax, int mmax) {
  __shared__ ushort As[128 * 64];
  __shared__ ushort Bs[128 * 64];
  const int t = threadIdx.x;
  const int lane = t & 63;
  const int wave = t >> 6;
  const int wm = (wave >> 1) << 6;
  const int wn = (wave & 1) << 6;
  const int quad = lane >> 4;
  const int ln = lane & 15;
  const size_t m0 = (size_t)blockIdx.x * 128;
  const size_t n0 = (size_t)blockIdx.y * 128;

  f32x4 acc[4][4];
#pragma unroll
  for (int x = 0; x < 4; ++x)
#pragma unroll
    for (int y = 0; y < 4; ++y)
      acc[x][y] = (f32x4){0.f, 0.f, 0.f, 0.f};

  for (int k0 = 0; k0 < 256; k0 += 64) {
    __syncthreads();
#pragma unroll
    for (int i = 0; i < 4; ++i) {
      const int f = i * 256 + t;
      const int row = f >> 3;
      const int cl = (f & 7) ^ (row & 7);
      const int ldsbase = (i * 256 + (t & ~63)) << 3;
      __builtin_amdgcn_global_load_lds(
          (const __attribute__((address_space(1))) void*)(A + (m0 + row) * 256 + k0 + cl * 8),
          (__attribute__((address_space(3))) void*)(As + ldsbase), 16, 0, 0);
      __builtin_amdgcn_global_load_lds(
          (const __attribute__((address_space(1))) void*)(Bt + (n0 + row) * 256 + k0 + cl * 8),
          (__attribute__((address_space(3))) void*)(Bs + ldsbase), 16, 0, 0);
    }
    __syncthreads();
#pragma unroll
    for (int s = 0; s < 2; ++s) {
      bf16x8 af[4], bfr[4];
      const int cl = s * 4 + quad;
#pragma unroll
      for (int x = 0; x < 4; ++x) {
        const int mm = wm + x * 16 + ln;
        af[x] = *(const bf16x8*)(As + mm * 64 + ((cl ^ (mm & 7)) << 3));
        const int nn = wn + x * 16 + ln;
        bfr[x] = *(const bf16x8*)(Bs + nn * 64 + ((cl ^ (nn & 7)) << 3));
      }
#pragma unroll
      for (int x = 0; x < 4; ++x)
#pragma unroll
        for (int y = 0; y < 4; ++y)
          acc[x][y] = __builtin_amdgcn_mfma_f32_16x16x32_bf16(bfr[y], af[x], acc[x][y], 0, 0, 0);
    }
  }

#pragma unroll
  for (int x = 0; x < 4; ++x) {
    const int m = (int)m0 + wm + x * 16 + ln;
    if (m < mmax) {
#pragma unroll
      for (int y = 0; y < 4; ++y) {
        const int n = (int)n0 + wn + y * 16 + quad * 4;
#pragma unroll
        for (int r = 0; r < 4; ++r)
          if (n + r < nmax)
            C[(size_t)m * ldc + n + r] = acc[x][y][r] + obias[n + r];
      }
    }
  }
}

// ---------------------------------------------------------------------------
// Fused per-node attention: one wave per node walks its (node,etype) CSR
// segments, computes w = exp(leakyrelu(el[src]+er[node])), shuffle-reduces
// the per-head denominator across the 16 edge-slots (lanes grouped (eo,h)),
// and writes NORMALIZED fp16 alphas to wcsr. No atomics, no extra passes for
// deg<=16 (covers nearly all segments at mean degree 5).
// ---------------------------------------------------------------------------
__global__ __launch_bounds__(256) void wden_kernel(const int* __restrict__ rowp3,
                                                   const uint* __restrict__ srcid,
                                                   const float* __restrict__ el,
                                                   const float* __restrict__ er,
                                                   ushort* __restrict__ wcsr) {
  const int wv   = __builtin_amdgcn_readfirstlane((int)(threadIdx.x >> 6));
  const int lane = threadIdx.x & 63;
  const int h    = lane & 3;     // head
  const int eo   = lane >> 2;    // edge slot 0..15
  for (int n = blockIdx.x * 4 + wv; n < N_NODES; n += 8192) {
#pragma unroll
    for (int et = 0; et < 3; ++et) {
      const int b = rowp3[n * 3 + et];
      const int e = rowp3[n * 3 + et + 1];
      const int deg = e - b;
      if (deg == 0) continue;
      const float erh = er[(((size_t)et * M_PAD + n) << 2) + h];
      if (deg <= 16) {
        const int idx = b + eo;
        const bool valid = idx < e;
        const uint sid = srcid[valid ? idx : b];
        float z = el[((size_t)sid << 2) + h] + erh;
        z = (z > 0.f) ? z : 0.2f * z;
        const float w = valid ? __expf(z) : 0.f;
        float s = w;
        s += __shfl_xor(s, 4);  s += __shfl_xor(s, 8);
        s += __shfl_xor(s, 16); s += __shfl_xor(s, 32);
        const float r = __builtin_amdgcn_rcpf(s);
        if (valid)
          wcsr[((size_t)idx << 2) + h] = __half_as_ushort(__float2half(w * r));
      } else {
        float s = 0.f;
        for (int i0 = b; i0 < e; i0 += 16) {
          const int idx = i0 + eo;
          const bool valid = idx < e;
          const uint sid = srcid[valid ? idx : b];
          float z = el[((size_t)sid << 2) + h] + erh;
          z = (z > 0.f) ? z : 0.2f * z;
          const float w = valid ? __expf(z) : 0.f;
          if (valid)
            wcsr[((size_t)idx << 2) + h] = __half_as_ushort(__float2half(w));
          s += w;
        }
        s += __shfl_xor(s, 4);  s += __shfl_xor(s, 8);
        s += __shfl_xor(s, 16); s += __shfl_xor(s, 32);
        const float r = __builtin_amdgcn_rcpf(s);
        for (int i0 = b; i0 < e; i0 += 16) {
          const int idx = i0 + eo;
          if (idx < e) {
            const float w = __half2float(__ushort_as_half(wcsr[((size_t)idx << 2) + h]));
            wcsr[((size_t)idx << 2) + h] = __half_as_ushort(__float2half(w * r));
          }
        }
      }
    }
  }
}

// ---------------------------------------------------------------------------
// Aggregation: combined CSR (all etypes per node, pre-normalized weights)
// -> single flat sum. Wave-strided node loop (2048 resident blocks) removes
// block-granularity load imbalance; node id wave-uniform so rowp3/srcid reads
// are scalar loads and gathers are SGPR-base + lane-constant voffset.
// ---------------------------------------------------------------------------
__global__ __launch_bounds__(256) void agg_kernel(const ushort* __restrict__ feat,
                                                  const ushort* __restrict__ wcsr,
                                                  const int* __restrict__ rowp3,
                                                  const uint* __restrict__ srcid,
                                                  const float* __restrict__ bias,
                                                  ushort* __restrict__ hout,
                                                  int layer, int do_relu) {
  const int wv   = __builtin_amdgcn_readfirstlane((int)(threadIdx.x >> 6));
  const int lane = threadIdx.x & 63;
  const int h2   = (lane >> 4) << 1;          // byte offset into 8B weight rec
  const int f8   = lane << 3;                 // byte offset into 512B feat row
  const float* bl = bias + layer * 768 + (lane << 2);
  const float b0 = bl[0] + bl[256] + bl[512];
  const float b1 = bl[1] + bl[257] + bl[513];
  const float b2 = bl[2] + bl[258] + bl[514];
  const float b3 = bl[3] + bl[259] + bl[515];
  const char* wb = (const char*)wcsr;
  const char* fb = (const char*)feat;
  for (int n = blockIdx.x * 4 + wv; n < N_NODES; n += 8192) {
    const int beg = rowp3[n * 3];
    const int end = rowp3[n * 3 + 3];
    float a0 = b0, a1 = b1, a2 = b2, a3 = b3;
    if (end > beg) {
      const int last = end - 1;
      float l0 = 0.f, l1 = 0.f, l2 = 0.f, l3 = 0.f;
      for (int i = beg; i < end; i += 8) {
        int idx[8];
#pragma unroll
        for (int j = 0; j < 8; ++j)
          idx[j] = (i + j < last) ? (i + j) : last;   // clamp: always valid
        uint sd[8];
#pragma unroll
        for (int j = 0; j < 8; ++j)
          sd[j] = srcid[idx[j]];
        float wj[8];
#pragma unroll
        for (int j = 0; j < 8; ++j) {
          const ushort wu = *(const ushort*)(wb + ((size_t)idx[j] << 3) + h2);
          const float t = __half2float(__ushort_as_half(wu));
          wj[j] = (i + j <= last) ? t : 0.f;          // branchless remainder
        }
        uint2 fv[8];
#pragma unroll
        for (int j = 0; j < 8; ++j)
          fv[j] = *(const uint2*)(fb + ((size_t)sd[j] << 9) + f8);
#pragma unroll
        for (int j = 0; j < 8; ++j) {
          union { uint u; float f; } c0, c1, c2, c3;
          c0.u = fv[j].x << 16;
          c1.u = fv[j].x & 0xffff0000u;
          c2.u = fv[j].y << 16;
          c3.u = fv[j].y & 0xffff0000u;
          l0 += wj[j] * c0.f;
          l1 += wj[j] * c1.f;
          l2 += wj[j] * c2.f;
          l3 += wj[j] * c3.f;
        }
      }
      a0 += l0; a1 += l1; a2 += l2; a3 += l3;
    }
    if (do_relu) {
      a0 = fmaxf(a0, 0.f); a1 = fmaxf(a1, 0.f);
      a2 = fmaxf(a2, 0.f); a3 = fmaxf(a3, 0.f);
    }
    ushort4 o;
    o.x = f2bf(a0); o.y = f2bf(a1); o.z = f2bf(a2); o.w = f2bf(a3);
    *(ushort4*)(hout + (size_t)n * 256 + (lane << 2)) = o;
  }
}

// ---------------------------------------------------------------------------
extern "C" void kernel_launch(void* const* d_in, const int* in_sizes, int n_in,
                              void* d_out, int out_size, void* d_ws, size_t ws_size,
                              hipStream_t stream) {
  const float* x      = (const float*)d_in[0];
  const float* W      = (const float*)d_in[1];
  const float* attn_l = (const float*)d_in[2];
  const float* attn_r = (const float*)d_in[3];
  const float* bias   = (const float*)d_in[4];
  const float* W_out  = (const float*)d_in[5];
  const float* b_out  = (const float*)d_in[6];
  const int*   src    = (const int*)d_in[7];
  const int*   dst    = (const int*)d_in[8];

  char* p = (char*)d_ws;
  auto carve = [&](size_t bytes) {
    char* r = p;
    p += (bytes + 255) & ~(size_t)255;
    return r;
  };
  ushort* h_bf  = (ushort*)carve((size_t)M_PAD * 256 * 2);        //  51.2 MB
  ushort* feat  = (ushort*)carve((size_t)3 * M_PAD * 256 * 2);    // 153.7 MB
  ushort* Wt    = (ushort*)carve((size_t)6 * 65536 * 2);
  ushort* Wto   = (ushort*)carve((size_t)384 * 256 * 2);
  float*  el    = (float*)carve((size_t)3 * M_PAD * 4 * 4);       //   4.8 MB
  float*  er    = (float*)carve((size_t)3 * M_PAD * 4 * 4);       //   4.8 MB
  int*    cnt   = (int*)carve((size_t)N3 * 4);
  int*    rowp3 = (int*)carve((size_t)(N3 + 1) * 4);
  int*    cur   = (int*)carve((size_t)N3 * 4);
  uint*   srcid = (uint*)carve((size_t)3 * N_EDGES * 4);          //   6 MB
  ushort* wcsr  = (ushort*)carve((size_t)3 * N_EDGES * 4 * 2);    //  12 MB (fp16)
  int*    bsum  = (int*)carve((size_t)NCHUNK3 * 4);

  cvt_x_kernel<<<M_PAD * 64 / 256, 256, 0, stream>>>(x, h_bf);
  cvt_w_kernel<<<6 * 65536 / 256, 256, 0, stream>>>(W, Wt);
  cvt_wout_kernel<<<384 * 256 / 256, 256, 0, stream>>>(W_out, Wto);

  zero_cnt_kernel<<<(N3 + 255) / 256, 256, 0, stream>>>(cnt);
  hist_kernel<<<(3 * N_EDGES + 255) / 256, 256, 0, stream>>>(dst, cnt);
  scan1_kernel<<<NCHUNK3, 512, 0, stream>>>(cnt, rowp3, bsum);
  scan2_kernel<<<1, 1024, 0, stream>>>(bsum);
  scan3_kernel<<<NCHUNK3, 512, 0, stream>>>(rowp3, bsum, cur);
  scatter_kernel<<<(3 * N_EDGES + 255) / 256, 256, 0, stream>>>(src, dst, cur, srcid);

  for (int l = 0; l < 2; ++l) {
    gemm_feat_fused<<<dim3(M_PAD / 128, 2), 256, 0, stream>>>(
        h_bf, Wt + (size_t)l * 3 * 65536, feat, attn_l, attn_r, el, er, l);
    wden_kernel<<<2048, 256, 0, stream>>>(rowp3, srcid, el, er, wcsr);
    agg_kernel<<<2048, 256, 0, stream>>>(feat, wcsr, rowp3, srcid, bias,
                                         h_bf, l, l == 0 ? 1 : 0);
  }
  gemm128<<<dim3(M_PAD / 128, 3), 256, 0, stream>>>(h_bf, Wto, (float*)d_out,
                                                    b_out, 349, 349, N_NODES);
}

// Round 3
// 867.343 us; speedup vs baseline: 1.7467x; 1.1412x over previous
//
#include <hip/hip_runtime.h>
#include <hip/hip_fp16.h>

#define N_NODES 100000
#define N_EDGES 500000
#define M_PAD   100096   // 782 * 128
#define N3      300000   // 3 * N_NODES (node-major, etype-minor keys)
#define NPB     512      // nodes per bucket (power of 2)
#define NBUK    196      // ceil(N_NODES / NPB)
#define KEYS_B  1536     // NPB * 3 keys per bucket
#define BCAP    12288    // bucket capacity (mean fill 7680, sigma 87)
#define CH_A    8192     // edges per bucketA block
#define NBLK_A  184      // ceil(3*N_EDGES / CH_A)

using f32x4  = __attribute__((ext_vector_type(4))) float;
using bf16x8 = __attribute__((ext_vector_type(8))) __bf16;

__device__ __forceinline__ ushort f2bf(float f) {
  union { float f; unsigned u; } v; v.f = f;
  unsigned r = v.u + 0x7fffu + ((v.u >> 16) & 1u);   // RNE
  return (ushort)(r >> 16);
}
__device__ __forceinline__ float bf2f(ushort b) {
  union { unsigned u; float f; } v; v.u = ((unsigned)b) << 16;
  return v.f;
}

// ---------------------------------------------------------------------------
// Conversions
// ---------------------------------------------------------------------------
__global__ __launch_bounds__(256) void cvt_x_kernel(const float* __restrict__ x,
                                                    ushort* __restrict__ h) {
  const size_t i = (size_t)blockIdx.x * 256 + threadIdx.x;  // float4 index
  ushort4 o;
  if (i < (size_t)N_NODES * 64) {
    const float4 v = ((const float4*)x)[i];
    o.x = f2bf(v.x); o.y = f2bf(v.y); o.z = f2bf(v.z); o.w = f2bf(v.w);
  } else {
    o.x = 0; o.y = 0; o.z = 0; o.w = 0;   // zero pad rows -> zero feat rows
  }
  ((ushort4*)h)[i] = o;
}

// W [le][k][n] fp32 -> Wt [le][n][k] bf16
__global__ __launch_bounds__(256) void cvt_w_kernel(const float* __restrict__ W,
                                                    ushort* __restrict__ Wt) {
  const int i = blockIdx.x * 256 + threadIdx.x;       // 6*65536
  const int le = i >> 16, r = i & 65535, nn = r >> 8, kk = r & 255;
  Wt[i] = f2bf(W[(le << 16) | (kk << 8) | nn]);
}

// W_out [256][349] -> Wto [384][256] bf16 transposed, zero-padded cols
__global__ __launch_bounds__(256) void cvt_wout_kernel(const float* __restrict__ Wo,
                                                       ushort* __restrict__ Wto) {
  const int i = blockIdx.x * 256 + threadIdx.x;       // 384*256
  const int nn = i >> 8, kk = i & 255;
  Wto[i] = f2bf(nn < 349 ? Wo[kk * 349 + nn] : 0.f);
}

// ---------------------------------------------------------------------------
// Atomic-light CSR build, grouped by (dst node, etype).
// Phase A: LDS-counted bucket scatter (bucket = dst>>9), one global atomic
// per (block,bucket) to reserve ranges; packed 4B records key<<19|srcid.
// Phase B: per-bucket LDS histogram + scan -> rowp3 + coalesced-window srcid.
// ---------------------------------------------------------------------------
__global__ __launch_bounds__(256) void zero_gcnt_kernel(int* __restrict__ gcnt) {
  const int i = threadIdx.x;
  if (i < NBUK) gcnt[i] = 0;
}

__global__ __launch_bounds__(256) void bucketA_kernel(const int* __restrict__ src,
                                                      const int* __restrict__ dst,
                                                      int* __restrict__ gcnt,
                                                      uint* __restrict__ barr) {
  __shared__ int cnt[NBUK];
  __shared__ int ofs[NBUK];
  const int t = threadIdx.x;
  const int base = blockIdx.x * CH_A;
  const int lim = (3 * N_EDGES - base < CH_A) ? (3 * N_EDGES - base) : CH_A;
  for (int b = t; b < NBUK; b += 256) cnt[b] = 0;
  __syncthreads();
  for (int k = t; k < lim; k += 256) {
    const int d = dst[base + k];
    atomicAdd(&cnt[d >> 9], 1);
  }
  __syncthreads();
  if (t < NBUK) {
    ofs[t] = atomicAdd(&gcnt[t], cnt[t]);
    cnt[t] = 0;
  }
  __syncthreads();
  for (int k = t; k < lim; k += 256) {
    const int i = base + k;
    const int d = dst[i];
    const int et = (i >= 2 * N_EDGES) ? 2 : ((i >= N_EDGES) ? 1 : 0);
    const uint key = (uint)((d & (NPB - 1)) * 3 + et);
    const uint sid = (uint)(et * M_PAD + src[i]);
    const int buk = d >> 9;
    int pos = ofs[buk] + atomicAdd(&cnt[buk], 1);
    if (pos < BCAP)
      barr[(size_t)buk * BCAP + pos] = (key << 19) | sid;
  }
}

__global__ __launch_bounds__(256) void scan196_kernel(const int* __restrict__ gcnt,
                                                      int* __restrict__ bbase,
                                                      int* __restrict__ rowp3) {
  __shared__ int sm[256];
  const int t = threadIdx.x;
  const int v = (t < NBUK) ? gcnt[t] : 0;
  sm[t] = v; __syncthreads();
  for (int off = 1; off < 256; off <<= 1) {
    const int x = (t >= off) ? sm[t - off] : 0;
    __syncthreads();
    sm[t] += x;
    __syncthreads();
  }
  if (t < NBUK) bbase[t] = sm[t] - v;   // exclusive
  if (t == 0) rowp3[N3] = 3 * N_EDGES;
}

__global__ __launch_bounds__(256) void csrB_kernel(const uint* __restrict__ barr,
                                                   const int* __restrict__ gcnt,
                                                   const int* __restrict__ bbase,
                                                   int* __restrict__ rowp3,
                                                   uint* __restrict__ srcid) {
  __shared__ int hist[KEYS_B];
  __shared__ int excl[KEYS_B];
  __shared__ int tsum[256];
  const int b = blockIdx.x, t = threadIdx.x;
  const int n = gcnt[b] < BCAP ? gcnt[b] : BCAP;
  const int cbase = bbase[b];
  const uint* ba = barr + (size_t)b * BCAP;
  for (int k = t; k < KEYS_B; k += 256) hist[k] = 0;
  __syncthreads();
  for (int r = t; r < n; r += 256) atomicAdd(&hist[ba[r] >> 19], 1);
  __syncthreads();
  // 256-thread scan over 1536 bins: thread t owns bins [6t, 6t+6)
  int loc[6];
  int s = 0;
#pragma unroll
  for (int j = 0; j < 6; ++j) { loc[j] = s; s += hist[t * 6 + j]; }
  tsum[t] = s; __syncthreads();
  for (int off = 1; off < 256; off <<= 1) {
    const int x = (t >= off) ? tsum[t - off] : 0;
    __syncthreads();
    tsum[t] += x;
    __syncthreads();
  }
  const int tbase = tsum[t] - s;    // exclusive over threads
#pragma unroll
  for (int j = 0; j < 6; ++j) excl[t * 6 + j] = tbase + loc[j];
  __syncthreads();
  // write rowp3 (global key id = b*KEYS_B + k = node*3 + et), reset cursors
  const int nrem = (N_NODES - b * NPB) * 3;
  const int kmax = (nrem < KEYS_B) ? nrem : KEYS_B;
  for (int k = t; k < KEYS_B; k += 256) {
    if (k < kmax) rowp3[b * KEYS_B + k] = cbase + excl[k];
    hist[k] = 0;
  }
  __syncthreads();
  for (int r = t; r < n; r += 256) {
    const uint rec = ba[r];
    const int key = (int)(rec >> 19);
    const int pos = excl[key] + atomicAdd(&hist[key], 1);
    srcid[cbase + pos] = rec & 0x7FFFFu;
  }
}

// ---------------------------------------------------------------------------
// Fused feat GEMM: 128x128 tile for all 3 etypes, shared A tile; epilogue
// writes feat (bf16) and el/er (pitch M_PAD) via in-register head-dots.
// ---------------------------------------------------------------------------
__global__ __launch_bounds__(256, 2) void gemm_feat_fused(
    const ushort* __restrict__ A, const ushort* __restrict__ WtL,
    ushort* __restrict__ feat, const float* __restrict__ attn_l,
    const float* __restrict__ attn_r, float* __restrict__ el,
    float* __restrict__ er, int layer) {
  __shared__ ushort As[128 * 64];
  __shared__ ushort Bs[3 * 128 * 64];
  const int t = threadIdx.x;
  const int lane = t & 63;
  const int wave = t >> 6;
  const int wm = (wave >> 1) << 6;
  const int wn = (wave & 1) << 6;
  const int quad = lane >> 4;
  const int ln = lane & 15;
  const size_t m0 = (size_t)blockIdx.x * 128;
  const size_t n0 = (size_t)blockIdx.y * 128;

  f32x4 acc[3][4][4];
#pragma unroll
  for (int e = 0; e < 3; ++e)
#pragma unroll
    for (int x = 0; x < 4; ++x)
#pragma unroll
      for (int y = 0; y < 4; ++y)
        acc[e][x][y] = (f32x4){0.f, 0.f, 0.f, 0.f};

  for (int k0 = 0; k0 < 256; k0 += 64) {
    __syncthreads();
#pragma unroll
    for (int i = 0; i < 4; ++i) {
      const int f = i * 256 + t;
      const int row = f >> 3;
      const int cl = (f & 7) ^ (row & 7);                 // global-side swizzle
      const int ldsbase = (i * 256 + (t & ~63)) << 3;     // wave-uniform, ushort idx
      __builtin_amdgcn_global_load_lds(
          (const __attribute__((address_space(1))) void*)(A + (m0 + row) * 256 + k0 + cl * 8),
          (__attribute__((address_space(3))) void*)(As + ldsbase), 16, 0, 0);
#pragma unroll
      for (int e = 0; e < 3; ++e)
        __builtin_amdgcn_global_load_lds(
            (const __attribute__((address_space(1))) void*)(WtL + (e << 16) + (n0 + row) * 256 + k0 + cl * 8),
            (__attribute__((address_space(3))) void*)(Bs + e * 8192 + ldsbase), 16, 0, 0);
    }
    __syncthreads();
#pragma unroll
    for (int s = 0; s < 2; ++s) {
      const int cl = s * 4 + quad;
      bf16x8 af[4];
#pragma unroll
      for (int x = 0; x < 4; ++x) {
        const int mm = wm + x * 16 + ln;
        af[x] = *(const bf16x8*)(As + mm * 64 + ((cl ^ (mm & 7)) << 3));
      }
#pragma unroll
      for (int e = 0; e < 3; ++e) {
        bf16x8 bfr[4];
#pragma unroll
        for (int y = 0; y < 4; ++y) {
          const int nn = wn + y * 16 + ln;
          bfr[y] = *(const bf16x8*)(Bs + e * 8192 + nn * 64 + ((cl ^ (nn & 7)) << 3));
        }
#pragma unroll
        for (int x = 0; x < 4; ++x)
#pragma unroll
          for (int y = 0; y < 4; ++y)
            acc[e][x][y] = __builtin_amdgcn_mfma_f32_16x16x32_bf16(bfr[y], af[x], acc[e][x][y], 0, 0, 0);
      }
    }
  }

  const int h = (int)(n0 + wn) >> 6;                      // this wave's head
#pragma unroll
  for (int e = 0; e < 3; ++e) {
    ushort* C = feat + (size_t)e * M_PAD * 256;
#pragma unroll
    for (int x = 0; x < 4; ++x) {
      const size_t m = m0 + wm + x * 16 + ln;
#pragma unroll
      for (int y = 0; y < 4; ++y) {
        const size_t n = n0 + wn + y * 16 + quad * 4;
        ushort4 o;
        o.x = f2bf(acc[e][x][y][0]); o.y = f2bf(acc[e][x][y][1]);
        o.z = f2bf(acc[e][x][y][2]); o.w = f2bf(acc[e][x][y][3]);
        *(ushort4*)(C + m * 256 + n) = o;
      }
    }
    const float* al = attn_l + (((layer * 3 + e) * 4 + h) << 6);
    const float* ar = attn_r + (((layer * 3 + e) * 4 + h) << 6);
    float4 alv[4], arv[4];
#pragma unroll
    for (int y = 0; y < 4; ++y) {
      alv[y] = *(const float4*)(al + y * 16 + quad * 4);
      arv[y] = *(const float4*)(ar + y * 16 + quad * 4);
    }
#pragma unroll
    for (int x = 0; x < 4; ++x) {
      float pl = 0.f, pr = 0.f;
#pragma unroll
      for (int y = 0; y < 4; ++y) {
        pl += acc[e][x][y][0] * alv[y].x + acc[e][x][y][1] * alv[y].y +
              acc[e][x][y][2] * alv[y].z + acc[e][x][y][3] * alv[y].w;
        pr += acc[e][x][y][0] * arv[y].x + acc[e][x][y][1] * arv[y].y +
              acc[e][x][y][2] * arv[y].z + acc[e][x][y][3] * arv[y].w;
      }
      pl += __shfl_xor(pl, 16); pl += __shfl_xor(pl, 32);
      pr += __shfl_xor(pr, 16); pr += __shfl_xor(pr, 32);
      const int m = (int)m0 + wm + x * 16 + ln;
      if (quad == 0 && m < N_NODES) {
        el[((size_t)e * M_PAD + m) * 4 + h] = pl;
        er[((size_t)e * M_PAD + m) * 4 + h] = pr;
      }
    }
  }
}

// ---------------------------------------------------------------------------
// Final classifier GEMM (fp32 out + bias, guarded).
// ---------------------------------------------------------------------------
__global__ __launch_bounds__(256) void gemm128(const ushort* __restrict__ A,
                                               const ushort* __restrict__ Bt,
                                               float* __restrict__ C,
                                               const float* __restrict__ obias,
                                               int ldc, int nmax, int mmax) {
  __shared__ ushort As[128 * 64];
  __shared__ ushort Bs[128 * 64];
  const int t = threadIdx.x;
  const int lane = t & 63;
  const int wave = t >> 6;
  const int wm = (wave >> 1) << 6;
  const int wn = (wave & 1) << 6;
  const int quad = lane >> 4;
  const int ln = lane & 15;
  const size_t m0 = (size_t)blockIdx.x * 128;
  const size_t n0 = (size_t)blockIdx.y * 128;

  f32x4 acc[4][4];
#pragma unroll
  for (int x = 0; x < 4; ++x)
#pragma unroll
    for (int y = 0; y < 4; ++y)
      acc[x][y] = (f32x4){0.f, 0.f, 0.f, 0.f};

  for (int k0 = 0; k0 < 256; k0 += 64) {
    __syncthreads();
#pragma unroll
    for (int i = 0; i < 4; ++i) {
      const int f = i * 256 + t;
      const int row = f >> 3;
      const int cl = (f & 7) ^ (row & 7);
      const int ldsbase = (i * 256 + (t & ~63)) << 3;
      __builtin_amdgcn_global_load_lds(
          (const __attribute__((address_space(1))) void*)(A + (m0 + row) * 256 + k0 + cl * 8),
          (__attribute__((address_space(3))) void*)(As + ldsbase), 16, 0, 0);
      __builtin_amdgcn_global_load_lds(
          (const __attribute__((address_space(1))) void*)(Bt + (n0 + row) * 256 + k0 + cl * 8),
          (__attribute__((address_space(3))) void*)(Bs + ldsbase), 16, 0, 0);
    }
    __syncthreads();
#pragma unroll
    for (int s = 0; s < 2; ++s) {
      bf16x8 af[4], bfr[4];
      const int cl = s * 4 + quad;
#pragma unroll
      for (int x = 0; x < 4; ++x) {
        const int mm = wm + x * 16 + ln;
        af[x] = *(const bf16x8*)(As + mm * 64 + ((cl ^ (mm & 7)) << 3));
        const int nn = wn + x * 16 + ln;
        bfr[x] = *(const bf16x8*)(Bs + nn * 64 + ((cl ^ (nn & 7)) << 3));
      }
#pragma unroll
      for (int x = 0; x < 4; ++x)
#pragma unroll
        for (int y = 0; y < 4; ++y)
          acc[x][y] = __builtin_amdgcn_mfma_f32_16x16x32_bf16(bfr[y], af[x], acc[x][y], 0, 0, 0);
    }
  }

#pragma unroll
  for (int x = 0; x < 4; ++x) {
    const int m = (int)m0 + wm + x * 16 + ln;
    if (m < mmax) {
#pragma unroll
      for (int y = 0; y < 4; ++y) {
        const int n = (int)n0 + wn + y * 16 + quad * 4;
#pragma unroll
        for (int r = 0; r < 4; ++r)
          if (n + r < nmax)
            C[(size_t)m * ldc + n + r] = acc[x][y][r] + obias[n + r];
      }
    }
  }
}

// ---------------------------------------------------------------------------
// Fused per-node attention: one wave per node walks its (node,etype) CSR
// segments, computes w = exp(leakyrelu(el[src]+er[node])), shuffle-reduces
// the per-head denominator across the 16 edge-slots (lanes grouped (eo,h)),
// and writes NORMALIZED fp16 alphas to wcsr. No atomics.
// ---------------------------------------------------------------------------
__global__ __launch_bounds__(256) void wden_kernel(const int* __restrict__ rowp3,
                                                   const uint* __restrict__ srcid,
                                                   const float* __restrict__ el,
                                                   const float* __restrict__ er,
                                                   ushort* __restrict__ wcsr) {
  const int wv   = __builtin_amdgcn_readfirstlane((int)(threadIdx.x >> 6));
  const int lane = threadIdx.x & 63;
  const int h    = lane & 3;     // head
  const int eo   = lane >> 2;    // edge slot 0..15
  for (int n = blockIdx.x * 4 + wv; n < N_NODES; n += 8192) {
#pragma unroll
    for (int et = 0; et < 3; ++et) {
      const int b = rowp3[n * 3 + et];
      const int e = rowp3[n * 3 + et + 1];
      const int deg = e - b;
      if (deg == 0) continue;
      const float erh = er[(((size_t)et * M_PAD + n) << 2) + h];
      if (deg <= 16) {
        const int idx = b + eo;
        const bool valid = idx < e;
        const uint sid = srcid[valid ? idx : b];
        float z = el[((size_t)sid << 2) + h] + erh;
        z = (z > 0.f) ? z : 0.2f * z;
        const float w = valid ? __expf(z) : 0.f;
        float s = w;
        s += __shfl_xor(s, 4);  s += __shfl_xor(s, 8);
        s += __shfl_xor(s, 16); s += __shfl_xor(s, 32);
        const float r = __builtin_amdgcn_rcpf(s);
        if (valid)
          wcsr[((size_t)idx << 2) + h] = __half_as_ushort(__float2half(w * r));
      } else {
        float s = 0.f;
        for (int i0 = b; i0 < e; i0 += 16) {
          const int idx = i0 + eo;
          const bool valid = idx < e;
          const uint sid = srcid[valid ? idx : b];
          float z = el[((size_t)sid << 2) + h] + erh;
          z = (z > 0.f) ? z : 0.2f * z;
          const float w = valid ? __expf(z) : 0.f;
          if (valid)
            wcsr[((size_t)idx << 2) + h] = __half_as_ushort(__float2half(w));
          s += w;
        }
        s += __shfl_xor(s, 4);  s += __shfl_xor(s, 8);
        s += __shfl_xor(s, 16); s += __shfl_xor(s, 32);
        const float r = __builtin_amdgcn_rcpf(s);
        for (int i0 = b; i0 < e; i0 += 16) {
          const int idx = i0 + eo;
          if (idx < e) {
            const float w = __half2float(__ushort_as_half(wcsr[((size_t)idx << 2) + h]));
            wcsr[((size_t)idx << 2) + h] = __half_as_ushort(__float2half(w * r));
          }
        }
      }
    }
  }
}

// ---------------------------------------------------------------------------
// Aggregation: combined CSR (all etypes per node, pre-normalized weights)
// -> single flat sum. Wave-strided node loop (2048 resident blocks) removes
// block-granularity load imbalance.
// ---------------------------------------------------------------------------
__global__ __launch_bounds__(256) void agg_kernel(const ushort* __restrict__ feat,
                                                  const ushort* __restrict__ wcsr,
                                                  const int* __restrict__ rowp3,
                                                  const uint* __restrict__ srcid,
                                                  const float* __restrict__ bias,
                                                  ushort* __restrict__ hout,
                                                  int layer, int do_relu) {
  const int wv   = __builtin_amdgcn_readfirstlane((int)(threadIdx.x >> 6));
  const int lane = threadIdx.x & 63;
  const int h2   = (lane >> 4) << 1;          // byte offset into 8B weight rec
  const int f8   = lane << 3;                 // byte offset into 512B feat row
  const float* bl = bias + layer * 768 + (lane << 2);
  const float b0 = bl[0] + bl[256] + bl[512];
  const float b1 = bl[1] + bl[257] + bl[513];
  const float b2 = bl[2] + bl[258] + bl[514];
  const float b3 = bl[3] + bl[259] + bl[515];
  const char* wb = (const char*)wcsr;
  const char* fb = (const char*)feat;
  for (int n = blockIdx.x * 4 + wv; n < N_NODES; n += 8192) {
    const int beg = rowp3[n * 3];
    const int end = rowp3[n * 3 + 3];
    float a0 = b0, a1 = b1, a2 = b2, a3 = b3;
    if (end > beg) {
      const int last = end - 1;
      float l0 = 0.f, l1 = 0.f, l2 = 0.f, l3 = 0.f;
      for (int i = beg; i < end; i += 8) {
        int idx[8];
#pragma unroll
        for (int j = 0; j < 8; ++j)
          idx[j] = (i + j < last) ? (i + j) : last;   // clamp: always valid
        uint sd[8];
#pragma unroll
        for (int j = 0; j < 8; ++j)
          sd[j] = srcid[idx[j]];
        float wj[8];
#pragma unroll
        for (int j = 0; j < 8; ++j) {
          const ushort wu = *(const ushort*)(wb + ((size_t)idx[j] << 3) + h2);
          const float t = __half2float(__ushort_as_half(wu));
          wj[j] = (i + j <= last) ? t : 0.f;          // branchless remainder
        }
        uint2 fv[8];
#pragma unroll
        for (int j = 0; j < 8; ++j)
          fv[j] = *(const uint2*)(fb + ((size_t)sd[j] << 9) + f8);
#pragma unroll
        for (int j = 0; j < 8; ++j) {
          union { uint u; float f; } c0, c1, c2, c3;
          c0.u = fv[j].x << 16;
          c1.u = fv[j].x & 0xffff0000u;
          c2.u = fv[j].y << 16;
          c3.u = fv[j].y & 0xffff0000u;
          l0 += wj[j] * c0.f;
          l1 += wj[j] * c1.f;
          l2 += wj[j] * c2.f;
          l3 += wj[j] * c3.f;
        }
      }
      a0 += l0; a1 += l1; a2 += l2; a3 += l3;
    }
    if (do_relu) {
      a0 = fmaxf(a0, 0.f); a1 = fmaxf(a1, 0.f);
      a2 = fmaxf(a2, 0.f); a3 = fmaxf(a3, 0.f);
    }
    ushort4 o;
    o.x = f2bf(a0); o.y = f2bf(a1); o.z = f2bf(a2); o.w = f2bf(a3);
    *(ushort4*)(hout + (size_t)n * 256 + (lane << 2)) = o;
  }
}

// ---------------------------------------------------------------------------
extern "C" void kernel_launch(void* const* d_in, const int* in_sizes, int n_in,
                              void* d_out, int out_size, void* d_ws, size_t ws_size,
                              hipStream_t stream) {
  const float* x      = (const float*)d_in[0];
  const float* W      = (const float*)d_in[1];
  const float* attn_l = (const float*)d_in[2];
  const float* attn_r = (const float*)d_in[3];
  const float* bias   = (const float*)d_in[4];
  const float* W_out  = (const float*)d_in[5];
  const float* b_out  = (const float*)d_in[6];
  const int*   src    = (const int*)d_in[7];
  const int*   dst    = (const int*)d_in[8];

  char* p = (char*)d_ws;
  auto carve = [&](size_t bytes) {
    char* r = p;
    p += (bytes + 255) & ~(size_t)255;
    return r;
  };
  ushort* h_bf  = (ushort*)carve((size_t)M_PAD * 256 * 2);        //  51.2 MB
  ushort* feat  = (ushort*)carve((size_t)3 * M_PAD * 256 * 2);    // 153.7 MB
  ushort* Wt    = (ushort*)carve((size_t)6 * 65536 * 2);
  ushort* Wto   = (ushort*)carve((size_t)384 * 256 * 2);
  float*  el    = (float*)carve((size_t)3 * M_PAD * 4 * 4);       //   4.8 MB
  float*  er    = (float*)carve((size_t)3 * M_PAD * 4 * 4);       //   4.8 MB
  int*    rowp3 = (int*)carve((size_t)(N3 + 1) * 4);
  uint*   srcid = (uint*)carve((size_t)3 * N_EDGES * 4);          //   6 MB
  ushort* wcsr  = (ushort*)carve((size_t)3 * N_EDGES * 4 * 2);    //  12 MB (fp16)
  uint*   barr  = (uint*)carve((size_t)NBUK * BCAP * 4);          //   9.6 MB
  int*    gcnt  = (int*)carve((size_t)NBUK * 4);
  int*    bbase = (int*)carve((size_t)NBUK * 4);

  cvt_x_kernel<<<M_PAD * 64 / 256, 256, 0, stream>>>(x, h_bf);
  cvt_w_kernel<<<6 * 65536 / 256, 256, 0, stream>>>(W, Wt);
  cvt_wout_kernel<<<384 * 256 / 256, 256, 0, stream>>>(W_out, Wto);

  zero_gcnt_kernel<<<1, 256, 0, stream>>>(gcnt);
  bucketA_kernel<<<NBLK_A, 256, 0, stream>>>(src, dst, gcnt, barr);
  scan196_kernel<<<1, 256, 0, stream>>>(gcnt, bbase, rowp3);
  csrB_kernel<<<NBUK, 256, 0, stream>>>(barr, gcnt, bbase, rowp3, srcid);

  for (int l = 0; l < 2; ++l) {
    gemm_feat_fused<<<dim3(M_PAD / 128, 2), 256, 0, stream>>>(
        h_bf, Wt + (size_t)l * 3 * 65536, feat, attn_l, attn_r, el, er, l);
    wden_kernel<<<2048, 256, 0, stream>>>(rowp3, srcid, el, er, wcsr);
    agg_kernel<<<2048, 256, 0, stream>>>(feat, wcsr, rowp3, srcid, bias,
                                         h_bf, l, l == 0 ? 1 : 0);
  }
  gemm128<<<dim3(M_PAD / 128, 3), 256, 0, stream>>>(h_bf, Wto, (float*)d_out,
                                                    b_out, 349, 349, N_NODES);
}